// Round 3
// baseline (762.170 us; speedup 1.0000x reference)
//
#include <hip/hip_runtime.h>
#include <hip/hip_bf16.h>
#include <hip/hip_cooperative_groups.h>

namespace cg = cooperative_groups;

#define EPSF 1e-8f

__device__ __forceinline__ float bflo(unsigned u) { return __uint_as_float(u << 16); }
__device__ __forceinline__ float bfhi(unsigned u) { return __uint_as_float(u & 0xffff0000u); }
__device__ __forceinline__ unsigned short bfr(float a) {
    union { __hip_bfloat16 h; unsigned short u; } cv;
    cv.h = __float2bfloat16(a);
    return cv.u;
}
__device__ __forceinline__ unsigned bfpack2(float a, float b) {
    return (unsigned)bfr(a) | ((unsigned)bfr(b) << 16);
}

// ===========================================================================
// Fused cooperative kernel: conv + all 3 routing iterations + stats + out.
// Grid 1024 x 256 = 16 waves/CU exactly (co-resident). Block = (b,h,wq):
// 8 w-positions x 32 ci. Thread (lw,ci) holds x[loc][c=0..127] as 64 packed
// bf16 VGPRs and B[loc][cj=0..31][ci] as 32 f32 VGPRs. Per 16-c chunk:
// products k*x staged to LDS (pad 33: <=2-way conflicts), S summed by
// (loc,c)-pair threads, squash, sh broadcast back via LDS, B updated from
// registers. Softmax stats: per-thread online over 32 cj -> 8-lw LDS reduce
// -> per-block partials -> grid.sync -> block 0 combines 128 partials per
// (b,ci) -> grid.sync. Entropy = (lnZ - T/Z)/ln(32768) at the final combine.
// ===========================================================================
__global__ __launch_bounds__(256, 4) void k_fused(
    const float* __restrict__ in, const float* __restrict__ cw,
    const float* __restrict__ cb, float* __restrict__ out,
    float* __restrict__ pm0, float* __restrict__ ps0,
    float* __restrict__ pm1, float* __restrict__ ps1, float* __restrict__ pt1,
    float* __restrict__ sm0, float* __restrict__ siz0,
    float* __restrict__ sm1, float* __restrict__ siz1) {
    cg::grid_group grid = cg::this_grid();

    __shared__ float prod[8][16][33];
    __shared__ float shl[8][16];
    __shared__ float red[3][8][33];
    __shared__ float entred[256];

    const int t   = threadIdx.x;
    const int ci  = t & 31;
    const int lw  = t >> 5;
    const int bid = blockIdx.x;          // 0..1023
    const int bh  = bid >> 2;
    const int b   = bh >> 5;
    const int h   = bh & 31;
    const int w   = ((bid & 3) << 3) + lw;

    // ---- conv: x[c] for c=0..127 -> packed bf16 registers -----------------
    float v[27];
#pragma unroll
    for (int kd = 0; kd < 3; ++kd)
#pragma unroll
        for (int dy = 0; dy < 3; ++dy) {
            const int y = h + dy - 1;
#pragma unroll
            for (int dx = 0; dx < 3; ++dx) {
                const int xx = w + dx - 1;
                float val = 0.0f;
                if ((unsigned)y < 32u && (unsigned)xx < 32u)
                    val = in[(((size_t)(b * 32 + ci) * 8 + kd) * 32 + y) * 32 + xx];
                v[kd * 9 + dy * 3 + dx] = val;
            }
        }

    unsigned xp[64];                      // x packed: xp[c>>1] = (x[c], x[c+1])
#pragma unroll
    for (int cp = 0; cp < 64; ++cp) {
        const float* w0 = cw + cp * 54;   // wave-uniform -> scalar loads
        float a0 = cb[cp * 2], a1 = cb[cp * 2 + 1];
#pragma unroll
        for (int k = 0; k < 27; ++k) a0 = fmaf(w0[k], v[k], a0);
#pragma unroll
        for (int k = 0; k < 27; ++k) a1 = fmaf(w0[27 + k], v[k], a1);
        xp[cp] = bfpack2(a0, a1);
    }

    float B32[32];
#pragma unroll
    for (int q = 0; q < 32; ++q) B32[q] = 0.0f;

    const int sidx = b * 32 + ci;

    // ---- 3 routing iterations ---------------------------------------------
#pragma unroll 1
    for (int it = 0; it < 3; ++it) {
        float smv = 0.0f, sizv = (1.0f / 32768.0f);
        if (it == 1)      { smv = sm0[sidx]; sizv = siz0[sidx]; }
        else if (it == 2) { smv = sm1[sidx]; sizv = siz1[sidx]; }

#pragma unroll
        for (int ch = 0; ch < 8; ++ch) {
            // products k[cj]*x[c] -> LDS
            float kv[4];
#pragma unroll
            for (int q = 0; q < 4; ++q)
                kv[q] = (it == 0) ? (1.0f / 32768.0f)
                                  : __expf(B32[ch * 4 + q] - smv) * sizv;
#pragma unroll
            for (int j = 0; j < 16; ++j) {
                const unsigned u = xp[ch * 8 + (j >> 1)];
                const float xv = (j & 1) ? bfhi(u) : bflo(u);
                prod[lw][j][ci] = kv[j >> 2] * xv;
            }
            __syncthreads();
            // S over ci: 2 threads per (loc,c) pair, 16 reads each + 1 shfl
            {
                const int p = t >> 1, half = t & 1;
                const int lw2 = p >> 4, j2 = p & 15;
                float s = 0.0f;
#pragma unroll
                for (int q = 0; q < 16; ++q) s += prod[lw2][j2][half * 16 + q];
                s += __shfl_xor(s, 1);
                const float sh = fabsf(s) * s / (1.0f + s * s + EPSF);  // squash
                if (half == 0) {
                    if (it == 2) {
                        const int c = ch * 16 + j2;
                        out[(((size_t)b * 128 + c) * 32 + h) * 32 +
                            ((bid & 3) << 3) + lw2] = sh;
                    } else {
                        shl[lw2][j2] = sh;
                    }
                }
            }
            __syncthreads();
            // B[cj] += sum_nj sh*x  (x from registers, sh broadcast from LDS)
            if (it < 2) {
#pragma unroll
                for (int j = 0; j < 16; ++j) {
                    const unsigned u = xp[ch * 8 + (j >> 1)];
                    const float xv = (j & 1) ? bfhi(u) : bflo(u);
                    B32[ch * 4 + (j >> 2)] = fmaf(shl[lw][j], xv, B32[ch * 4 + (j >> 2)]);
                }
            }
        }

        // ---- softmax stats of the just-updated B --------------------------
        if (it < 2) {
            float m = B32[0];
#pragma unroll
            for (int q = 1; q < 32; ++q) m = fmaxf(m, B32[q]);
            float s = 0.0f, tt = 0.0f;
#pragma unroll
            for (int q = 0; q < 32; ++q) {
                const float d = B32[q] - m;
                const float e = __expf(d);
                s += e; tt += e * d;
            }
            red[0][lw][ci] = m; red[1][lw][ci] = s; red[2][lw][ci] = tt;
            __syncthreads();
            if (lw == 0) {
                float M = red[0][0][ci];
#pragma unroll
                for (int q = 1; q < 8; ++q) M = fmaxf(M, red[0][q][ci]);
                float S = 0.0f, T = 0.0f;
#pragma unroll
                for (int q = 0; q < 8; ++q) {
                    const float dm = red[0][q][ci] - M;
                    const float e = __expf(dm);
                    S += red[1][q][ci] * e;
                    T += (red[2][q][ci] + red[1][q][ci] * dm) * e;
                }
                if (it == 0) { pm0[bid * 32 + ci] = M; ps0[bid * 32 + ci] = S; }
                else { pm1[bid * 32 + ci] = M; ps1[bid * 32 + ci] = S;
                       pt1[bid * 32 + ci] = T; }
            }
            grid.sync();
            // combine: block 0, thread = (b2,ci2), merge 128 block-partials
            if (bid == 0) {
                const int b2 = t >> 5, ci2 = t & 31;
                const float* PM = (it == 0) ? pm0 : pm1;
                const float* PS = (it == 0) ? ps0 : ps1;
                float M = -1e30f;
                for (int k2 = 0; k2 < 128; ++k2)
                    M = fmaxf(M, PM[(b2 * 128 + k2) * 32 + ci2]);
                float Z = 0.0f, T = 0.0f;
                for (int k2 = 0; k2 < 128; ++k2) {
                    const int i2 = (b2 * 128 + k2) * 32 + ci2;
                    const float dm = PM[i2] - M;
                    const float e = __expf(dm);
                    Z += PS[i2] * e;
                    if (it == 1) T += (pt1[i2] + PS[i2] * dm) * e;
                }
                if (it == 0) { sm0[t] = M; siz0[t] = 1.0f / Z; }
                else {
                    sm1[t] = M; siz1[t] = 1.0f / Z;
                    // ent = (lnZ - T/Z)/ln(32768); eps-in-log effect ~3e-5
                    const float ent = (__logf(Z) - T / Z) * (1.0f / 10.3972077084f);
                    entred[t] = ent;
                    __syncthreads();
                    for (int s2 = 128; s2 > 0; s2 >>= 1) {
                        if (t < s2) entred[t] += entred[t + s2];
                        __syncthreads();
                    }
                    if (t == 0) out[1048576] = entred[0] * (1.0f / 256.0f);
                }
            }
            grid.sync();
        }
    }
}

// ===========================================================================
// Fallback pipeline (round-2, proven): used only if cooperative launch fails.
// ===========================================================================
__global__ __launch_bounds__(256) void k_convb1(const float* __restrict__ in,
                                                const float* __restrict__ cw,
                                                const float* __restrict__ cb,
                                                __hip_bfloat16* __restrict__ x,
                                                float* __restrict__ B) {
    const int bh = blockIdx.x >> 2;
    const int b = bh >> 5, h = bh & 31;
    const int t = threadIdx.x;
    const int ci = t & 31;
    const int w = ((blockIdx.x & 3) << 3) + (t >> 5);

    float v[27];
#pragma unroll
    for (int kd = 0; kd < 3; ++kd) {
#pragma unroll
        for (int dy = 0; dy < 3; ++dy) {
            const int y = h + dy - 1;
            const bool yok = (y >= 0) && (y < 32);
#pragma unroll
            for (int dx = 0; dx < 3; ++dx) {
                const int xx = w + dx - 1;
                float val = 0.0f;
                if (yok && xx >= 0 && xx < 32)
                    val = in[(((size_t)(b * 32 + ci) * 8 + kd) * 32 + y) * 32 + xx];
                v[kd * 9 + dy * 3 + dx] = val;
            }
        }
    }

    const size_t loc = (size_t)bh * 32 + w;
    __hip_bfloat16* xrow = x + loc * 4096;
    float* Brow = B + loc * 1024;

    for (int cj = 0; cj < 32; ++cj) {
        float bacc = 0.0f;
#pragma unroll
        for (int nj = 0; nj < 4; ++nj) {
            const int c = cj * 4 + nj;
            const float* wc = cw + c * 27;
            float acc = cb[c];
#pragma unroll
            for (int k = 0; k < 27; ++k) acc = fmaf(wc[k], v[k], acc);
            float r = acc;
            r += __shfl_xor(r, 1);  r += __shfl_xor(r, 2);  r += __shfl_xor(r, 4);
            r += __shfl_xor(r, 8);  r += __shfl_xor(r, 16);
            const float S = r * (1.0f / 32768.0f);
            const float sh = fabsf(S) * S / (1.0f + S * S + EPSF);
            bacc = fmaf(sh, acc, bacc);
            xrow[c * 32 + ci] = __float2bfloat16(acc);
        }
        Brow[cj * 32 + ci] = bacc;
    }
}

__global__ __launch_bounds__(256) void k_stats_part(const float* __restrict__ B,
                                                    float* __restrict__ pm,
                                                    float* __restrict__ ps,
                                                    float* __restrict__ pt) {
    const int bh = blockIdx.x;
    const int t = threadIdx.x;
    const float4* Bp = reinterpret_cast<const float4*>(B) + (size_t)bh * 8192;

    float m0 = -1e30f, m1 = -1e30f, m2 = -1e30f, m3 = -1e30f;
#pragma unroll 4
    for (int j = 0; j < 32; ++j) {
        float4 f = Bp[t + j * 256];
        m0 = fmaxf(m0, f.x); m1 = fmaxf(m1, f.y); m2 = fmaxf(m2, f.z); m3 = fmaxf(m3, f.w);
    }
    __shared__ float red[32][33];
    __shared__ float bm[32];
    const int ciq = (t & 7) * 4, copy = t >> 3;
    red[ciq + 0][copy] = m0; red[ciq + 1][copy] = m1;
    red[ciq + 2][copy] = m2; red[ciq + 3][copy] = m3;
    __syncthreads();
    if (t < 32) {
        float M = red[t][0];
        for (int c = 1; c < 32; ++c) M = fmaxf(M, red[t][c]);
        bm[t] = M;
    }
    __syncthreads();
    const float M0 = bm[ciq], M1 = bm[ciq + 1], M2 = bm[ciq + 2], M3 = bm[ciq + 3];

    float s0 = 0, s1 = 0, s2 = 0, s3 = 0, T0 = 0, T1 = 0, T2 = 0, T3 = 0;
#pragma unroll 4
    for (int j = 0; j < 32; ++j) {
        float4 f = Bp[t + j * 256];
        float d, e;
        d = f.x - M0; e = expf(d); s0 += e; T0 += e * d;
        d = f.y - M1; e = expf(d); s1 += e; T1 += e * d;
        d = f.z - M2; e = expf(d); s2 += e; T2 += e * d;
        d = f.w - M3; e = expf(d); s3 += e; T3 += e * d;
    }
    __syncthreads();
    red[ciq + 0][copy] = s0; red[ciq + 1][copy] = s1;
    red[ciq + 2][copy] = s2; red[ciq + 3][copy] = s3;
    __syncthreads();
    if (t < 32) {
        float S = 0;
        for (int c = 0; c < 32; ++c) S += red[t][c];
        ps[bh * 32 + t] = S;
        pm[bh * 32 + t] = bm[t];
    }
    __syncthreads();
    red[ciq + 0][copy] = T0; red[ciq + 1][copy] = T1;
    red[ciq + 2][copy] = T2; red[ciq + 3][copy] = T3;
    __syncthreads();
    if (t < 32) {
        float S = 0;
        for (int c = 0; c < 32; ++c) S += red[t][c];
        pt[bh * 32 + t] = S;
    }
}

__global__ __launch_bounds__(256) void k_stats_comb(const float* __restrict__ pm,
                                                    const float* __restrict__ ps,
                                                    const float* __restrict__ pt,
                                                    float* __restrict__ sm,
                                                    float* __restrict__ siz,
                                                    float* __restrict__ d_ent,
                                                    int final_) {
    const int t = threadIdx.x;
    const int b = t >> 5;
    float M = -1e30f;
    for (int h = 0; h < 32; ++h) M = fmaxf(M, pm[(b * 32 + h) * 32 + (t & 31)]);
    float Z = 0.0f, T = 0.0f;
    for (int h = 0; h < 32; ++h) {
        const int i = (b * 32 + h) * 32 + (t & 31);
        const float dm = pm[i] - M;
        const float e = expf(dm);
        Z += ps[i] * e;
        T += e * (pt[i] + ps[i] * dm);
    }
    sm[t] = M;
    siz[t] = 1.0f / Z;
    if (final_) {
        const float ent = (logf(Z) - T / Z) / logf(32768.0f);
        __shared__ float red[256];
        red[t] = ent;
        __syncthreads();
        for (int s2 = 128; s2 > 0; s2 >>= 1) {
            if (t < s2) red[t] += red[t + s2];
            __syncthreads();
        }
        if (t == 0) *d_ent = red[0] * (1.0f / 256.0f);
    }
}

template <int FINAL>
__global__ __launch_bounds__(256) void k_iter(const __hip_bfloat16* __restrict__ x,
                                              float* __restrict__ B,
                                              const float* __restrict__ sm,
                                              const float* __restrict__ siz,
                                              float* __restrict__ shat) {
    __shared__ float s_m[32], s_z[32];
    __shared__ float p[2][128][33];
    const int t = threadIdx.x;
    const int bb = (int)(((size_t)blockIdx.x * 2) >> 10);
    if (t < 32) { s_m[t] = sm[bb * 32 + t]; s_z[t] = siz[bb * 32 + t]; }
    __syncthreads();

    const int l = t >> 7;
    const int u = t & 127;
    const int cj = u & 31;
    const int c = cj * 4 + (u >> 5);
    const size_t loc = (size_t)blockIdx.x * 2 + l;

    const uint4* xr = reinterpret_cast<const uint4*>(x + loc * 4096 + (size_t)c * 32);
    const float4* Br = reinterpret_cast<const float4*>(B + loc * 1024 + (size_t)cj * 32);

    uint4 qa = xr[0], qb = xr[1], qc = xr[2], qd = xr[3];
    const unsigned int ua[16] = {qa.x, qa.y, qa.z, qa.w, qb.x, qb.y, qb.z, qb.w,
                                 qc.x, qc.y, qc.z, qc.w, qd.x, qd.y, qd.z, qd.w};
    float xv[32];
#pragma unroll
    for (int k = 0; k < 16; ++k) { xv[2 * k] = bflo(ua[k]); xv[2 * k + 1] = bfhi(ua[k]); }

    float S = 0.0f;
#pragma unroll
    for (int j = 0; j < 8; ++j) {
        float4 bf = Br[j];
        S = fmaf(expf(bf.x - s_m[4 * j + 0]) * s_z[4 * j + 0], xv[4 * j + 0], S);
        S = fmaf(expf(bf.y - s_m[4 * j + 1]) * s_z[4 * j + 1], xv[4 * j + 1], S);
        S = fmaf(expf(bf.z - s_m[4 * j + 2]) * s_z[4 * j + 2], xv[4 * j + 2], S);
        S = fmaf(expf(bf.w - s_m[4 * j + 3]) * s_z[4 * j + 3], xv[4 * j + 3], S);
    }
    const float sh = fabsf(S) * S / (1.0f + S * S + EPSF);

    if constexpr (FINAL) {
        shat[loc * 128 + u] = sh;
    } else {
#pragma unroll
        for (int cc = 0; cc < 32; ++cc) p[l][u][cc] = sh * xv[cc];
        __syncthreads();
#pragma unroll
        for (int r = 0; r < 8; ++r) {
            const int pair = t + r * 256;
            const int l2 = pair >> 10, q = pair & 1023;
            const int cjq = q >> 5, ciq = q & 31;
            const size_t idx = ((size_t)blockIdx.x * 2 + l2) * 1024 + q;
            B[idx] += p[l2][cjq][ciq] + p[l2][32 + cjq][ciq] +
                      p[l2][64 + cjq][ciq] + p[l2][96 + cjq][ciq];
        }
    }
}

__global__ __launch_bounds__(256) void k_out(const float* __restrict__ shat,
                                             float* __restrict__ out) {
    __shared__ float tile[32][129];
    const int bh = blockIdx.x;
    const int b = bh >> 5, h = bh & 31;
    const int t = threadIdx.x;
    const float4* sp = reinterpret_cast<const float4*>(shat + (size_t)bh * 4096);
#pragma unroll
    for (int j = 0; j < 4; ++j) {
        const int idx = t + j * 256;
        const float4 f = sp[idx];
        const int w = idx >> 5;
        const int u4 = (idx & 31) * 4;
        tile[w][u4 + 0] = f.x; tile[w][u4 + 1] = f.y;
        tile[w][u4 + 2] = f.z; tile[w][u4 + 3] = f.w;
    }
    __syncthreads();
    const int cp = t >> 1, half = t & 1;
    const int u = (cp & 3) * 32 + (cp >> 2);
    float* op = out + (((size_t)b * 128 + cp) * 32 + h) * 32 + half * 16;
#pragma unroll
    for (int j = 0; j < 16; ++j) op[j] = tile[half * 16 + j][u];
}

// ===========================================================================
extern "C" void kernel_launch(void* const* d_in, const int* in_sizes, int n_in,
                              void* d_out, int out_size, void* d_ws, size_t ws_size,
                              hipStream_t stream) {
    const float* in = (const float*)d_in[0];   // (8,32,8,32,32)
    const float* cw = (const float*)d_in[1];   // (128,1,3,3,3)
    const float* cb = (const float*)d_in[2];   // (128,)
    float* out = (float*)d_out;                // 1048576 + 1 floats

    // fused-path workspace (tiny)
    float* pm0  = (float*)d_ws;                // [1024*32]
    float* ps0  = pm0 + 32768;
    float* pm1  = ps0 + 32768;
    float* ps1  = pm1 + 32768;
    float* pt1  = ps1 + 32768;
    float* sm0  = pt1 + 32768;                 // [256]
    float* siz0 = sm0 + 256;
    float* sm1  = siz0 + 256;
    float* siz1 = sm1 + 256;

    void* args[] = {(void*)&in, (void*)&cw, (void*)&cb, (void*)&out,
                    (void*)&pm0, (void*)&ps0, (void*)&pm1, (void*)&ps1, (void*)&pt1,
                    (void*)&sm0, (void*)&siz0, (void*)&sm1, (void*)&siz1};
    hipError_t err = hipLaunchCooperativeKernel(reinterpret_cast<void*>(k_fused),
                                                dim3(1024), dim3(256), args, 0, stream);
    if (err == hipSuccess) return;
    (void)hipGetLastError();   // clear sticky error, take proven fallback path

    // ---- fallback: round-2 pipeline ----
    __hip_bfloat16* x = (__hip_bfloat16*)d_ws;
    float* B     = (float*)(x + 33554432);
    float* shat  = B + 8388608;
    float* pmF   = shat + 1048576;
    float* psF   = pmF + 8192;
    float* ptF   = psF + 8192;
    float* smF   = ptF + 8192;
    float* sizF  = smF + 256;

    k_convb1<<<1024, 256, 0, stream>>>(in, cw, cb, x, B);
    k_stats_part<<<256, 256, 0, stream>>>(B, pmF, psF, ptF);
    k_stats_comb<<<1, 256, 0, stream>>>(pmF, psF, ptF, smF, sizF, out + 1048576, 0);
    k_iter<0><<<4096, 256, 0, stream>>>(x, B, smF, sizF, nullptr);
    k_stats_part<<<256, 256, 0, stream>>>(B, pmF, psF, ptF);
    k_stats_comb<<<1, 256, 0, stream>>>(pmF, psF, ptF, smF, sizF, out + 1048576, 1);
    k_iter<1><<<4096, 256, 0, stream>>>(x, B, smF, sizF, shat);
    k_out<<<256, 256, 0, stream>>>(shat, out);
}

// Round 4
// 149.866 us; speedup vs baseline: 5.0857x; 5.0857x over previous
//
#include <hip/hip_runtime.h>
#include <hip/hip_bf16.h>

#define EPSF 1e-8f

// Workspace:
//   xu   [loc][cp=0..63][ci=0..31]  u32 = (bf16 c=2cp | bf16 c=2cp+1 <<16)
//        loc=(b*32+h)*32+w ; 16,777,216 u32 = 64 MiB ; c = cj*4+nj, cp = c>>1
//   B    [loc][cj*32+ci] f32  (32 MiB)
//   shat [loc][c=0..127] f32  (4 MiB)   (c in OUTPUT channel order)
//   pm0/ps0 [1024 blocks][32ci] ; pmF/psF/ptF [256 bh][32] ; sm*/siz* [256]

__device__ __forceinline__ float bflo(unsigned u) { return __uint_as_float(u << 16); }
__device__ __forceinline__ float bfhi(unsigned u) { return __uint_as_float(u & 0xffff0000u); }
__device__ __forceinline__ unsigned bfpack2(float a, float b) {
    // truncation to bf16 (error 2x vs RNE; output slack is ~7 orders of magnitude)
    return (__float_as_uint(a) >> 16) | (__float_as_uint(b) & 0xffff0000u);
}
__device__ __forceinline__ float fastrcp(float x) { return __builtin_amdgcn_rcpf(x); }

// ---------------------------------------------------------------------------
// K1: conv (LDS-staged, coalesced) + iter0 (uniform k) + B1 + stats0 partials.
// block 256 = 8 w x 32 ci ; grid 1024 = (b,h,wq).
__global__ __launch_bounds__(256) void k_conv1(const float* __restrict__ in,
                                               const float* __restrict__ cw,
                                               const float* __restrict__ cb,
                                               unsigned* __restrict__ xu,
                                               float* __restrict__ B,
                                               float* __restrict__ pm0,
                                               float* __restrict__ ps0) {
    __shared__ float slab[288][17];   // row r = ci*9+kd*3+dy ; 16 x-values [w0-4,w0+12)
    __shared__ float red[2][8][33];

    const int t = threadIdx.x;
    const int ci = t & 31, lw = t >> 5;
    const int bid = blockIdx.x;
    const int bh = bid >> 2, b = bh >> 5, h = bh & 31;
    const int w0 = (bid & 3) << 3;

    // coalesced staging: 1152 float4 loads (zero-padded OOB; x0 aligned, all-in or all-out)
    for (int j = t; j < 1152; j += 256) {
        const int r = j >> 2, q = j & 3;
        const int ci2 = r / 9, rem = r - ci2 * 9, kd = rem / 3, dy = rem - kd * 3;
        const int y = h + dy - 1;
        const int x0 = w0 - 4 + q * 4;
        float4 f = {0.f, 0.f, 0.f, 0.f};
        if ((unsigned)y < 32u && (unsigned)x0 < 32u)
            f = *reinterpret_cast<const float4*>(
                in + (((size_t)(b * 32 + ci2) * 8 + kd) * 32 + y) * 32 + x0);
        slab[r][q * 4 + 0] = f.x; slab[r][q * 4 + 1] = f.y;
        slab[r][q * 4 + 2] = f.z; slab[r][q * 4 + 3] = f.w;
    }
    __syncthreads();

    float v[27];
#pragma unroll
    for (int kd = 0; kd < 3; ++kd)
#pragma unroll
        for (int dy = 0; dy < 3; ++dy)
#pragma unroll
            for (int dx = 0; dx < 3; ++dx)
                v[kd * 9 + dy * 3 + dx] = slab[ci * 9 + kd * 3 + dy][lw + 3 + dx];

    const size_t loc = (size_t)bh * 32 + w0 + lw;
    unsigned* xrow = xu + loc * 2048;
    float* Brow = B + loc * 1024;
    float Breg[32];

#pragma unroll
    for (int cj = 0; cj < 32; ++cj) {
        float bacc = 0.0f;
#pragma unroll
        for (int njh = 0; njh < 2; ++njh) {
            const int cp = cj * 2 + njh;
            const float* wp = cw + cp * 54;            // wave-uniform -> s_load
            float a0 = cb[cp * 2], a1 = cb[cp * 2 + 1];
#pragma unroll
            for (int k = 0; k < 27; ++k) a0 = fmaf(wp[k], v[k], a0);
#pragma unroll
            for (int k = 0; k < 27; ++k) a1 = fmaf(wp[27 + k], v[k], a1);
            float r0 = a0, r1 = a1;                    // sum over 32 ci lanes
            r0 += __shfl_xor(r0, 1);  r1 += __shfl_xor(r1, 1);
            r0 += __shfl_xor(r0, 2);  r1 += __shfl_xor(r1, 2);
            r0 += __shfl_xor(r0, 4);  r1 += __shfl_xor(r1, 4);
            r0 += __shfl_xor(r0, 8);  r1 += __shfl_xor(r1, 8);
            r0 += __shfl_xor(r0, 16); r1 += __shfl_xor(r1, 16);
            const float S0 = r0 * (1.0f / 32768.0f), S1 = r1 * (1.0f / 32768.0f);
            const float sh0 = fabsf(S0) * S0 * fastrcp(1.0f + S0 * S0 + EPSF);
            const float sh1 = fabsf(S1) * S1 * fastrcp(1.0f + S1 * S1 + EPSF);
            bacc = fmaf(sh0, a0, fmaf(sh1, a1, bacc));
            xrow[cp * 32 + ci] = bfpack2(a0, a1);
        }
        Breg[cj] = bacc;
        Brow[cj * 32 + ci] = bacc;                     // B starts at 0
    }

    // stats0 partial: per-(block,ci) max / sum-exp over (8 w, 32 cj)
    float m = Breg[0];
#pragma unroll
    for (int q = 1; q < 32; ++q) m = fmaxf(m, Breg[q]);
    float s = 0.0f;
#pragma unroll
    for (int q = 0; q < 32; ++q) s += __expf(Breg[q] - m);
    red[0][lw][ci] = m; red[1][lw][ci] = s;
    __syncthreads();
    if (lw == 0) {
        float M = red[0][0][ci];
#pragma unroll
        for (int q = 1; q < 8; ++q) M = fmaxf(M, red[0][q][ci]);
        float S = 0.0f;
#pragma unroll
        for (int q = 0; q < 8; ++q) S += red[1][q][ci] * __expf(red[0][q][ci] - M);
        pm0[bid * 32 + ci] = M;
        ps0[bid * 32 + ci] = S;
    }
}

// ---------------------------------------------------------------------------
// K2: combine 128 block-partials per (b,ci) -> sm0, siz0.
__global__ __launch_bounds__(256) void k_comb0(const float* __restrict__ pm,
                                               const float* __restrict__ ps,
                                               float* __restrict__ sm,
                                               float* __restrict__ siz) {
    const int t = threadIdx.x;            // b*32+ci
    const int b = t >> 5, ci = t & 31;
    float M = -1e30f;
    for (int k = 0; k < 128; ++k) M = fmaxf(M, pm[(b * 128 + k) * 32 + ci]);
    float Z = 0.0f;
    for (int k = 0; k < 128; ++k) {
        const int i = (b * 128 + k) * 32 + ci;
        Z += ps[i] * __expf(pm[i] - M);
    }
    sm[t] = M;
    siz[t] = 1.0f / Z;
}

// ---------------------------------------------------------------------------
// K3/K6: routing iteration. block 256 = 2 loc x 64 cp x 2 half(16 ci each).
// t -> l=t>>7, r=t&127, cp=r>>1, half=r&1, cj=cp>>1. Shfl partners in-wave:
// ^1 = other ci-half (S reduce), ^2 = other njh (B delta reduce).
template <int FINAL>
__global__ __launch_bounds__(256) void k_iter(const unsigned* __restrict__ xu,
                                              float* __restrict__ B,
                                              const float* __restrict__ sm,
                                              const float* __restrict__ siz,
                                              float* __restrict__ shat) {
    __shared__ float s_m[32], s_z[32];
    const int t = threadIdx.x;
    const size_t loc0 = (size_t)blockIdx.x * 2;
    const int b = (int)(loc0 >> 10);
    if (t < 32) { s_m[t] = sm[b * 32 + t]; s_z[t] = siz[b * 32 + t]; }
    __syncthreads();

    const int l = t >> 7, r = t & 127;
    const int cp = r >> 1, half = r & 1, cj = cp >> 1;
    const size_t loc = loc0 + l;

    const uint4* xr = reinterpret_cast<const uint4*>(xu + loc * 2048 + cp * 32 + half * 16);
    float4* Bp = reinterpret_cast<float4*>(B + loc * 1024 + cj * 32 + half * 16);

    uint4 xq[4];
    float4 Bf[4];
#pragma unroll
    for (int j = 0; j < 4; ++j) { xq[j] = xr[j]; Bf[j] = Bp[j]; }

    float S0 = 0.0f, S1 = 0.0f;
    const int cb0 = half * 16;
#pragma unroll
    for (int j = 0; j < 4; ++j) {
        const float bv[4] = {Bf[j].x, Bf[j].y, Bf[j].z, Bf[j].w};
        const unsigned xv[4] = {xq[j].x, xq[j].y, xq[j].z, xq[j].w};
#pragma unroll
        for (int q = 0; q < 4; ++q) {
            const int ciq = cb0 + j * 4 + q;
            const float k = __expf(bv[q] - s_m[ciq]) * s_z[ciq];
            S0 = fmaf(k, bflo(xv[q]), S0);
            S1 = fmaf(k, bfhi(xv[q]), S1);
        }
    }
    S0 += __shfl_xor(S0, 1);                 // combine ci halves
    S1 += __shfl_xor(S1, 1);
    const float sh0 = fabsf(S0) * S0 * fastrcp(1.0f + S0 * S0 + EPSF);
    const float sh1 = fabsf(S1) * S1 * fastrcp(1.0f + S1 * S1 + EPSF);

    if constexpr (FINAL) {
        if (half == 0)
            reinterpret_cast<float2*>(shat)[loc * 64 + cp] = make_float2(sh0, sh1);
    } else {
        float d[16];
#pragma unroll
        for (int j = 0; j < 4; ++j) {
            const unsigned xv[4] = {xq[j].x, xq[j].y, xq[j].z, xq[j].w};
#pragma unroll
            for (int q = 0; q < 4; ++q)
                d[j * 4 + q] = fmaf(sh0, bflo(xv[q]), sh1 * bfhi(xv[q]));
        }
#pragma unroll
        for (int q = 0; q < 16; ++q) d[q] += __shfl_xor(d[q], 2);   // sum over njh
        if ((r & 2) == 0) {
            float4 o;
#pragma unroll
            for (int j = 0; j < 4; ++j) {
                o.x = Bf[j].x + d[j * 4 + 0];
                o.y = Bf[j].y + d[j * 4 + 1];
                o.z = Bf[j].z + d[j * 4 + 2];
                o.w = Bf[j].w + d[j * 4 + 3];
                Bp[j] = o;
            }
        }
    }
}

// ---------------------------------------------------------------------------
// K4: softmax stats partials over B (per bh slice, per ci).
__global__ __launch_bounds__(256) void k_stats_part(const float* __restrict__ B,
                                                    float* __restrict__ pm,
                                                    float* __restrict__ ps,
                                                    float* __restrict__ pt) {
    const int bh = blockIdx.x;
    const int t = threadIdx.x;
    const float4* Bp = reinterpret_cast<const float4*>(B) + (size_t)bh * 8192;

    float m0 = -1e30f, m1 = -1e30f, m2 = -1e30f, m3 = -1e30f;
#pragma unroll 4
    for (int j = 0; j < 32; ++j) {
        float4 f = Bp[t + j * 256];
        m0 = fmaxf(m0, f.x); m1 = fmaxf(m1, f.y); m2 = fmaxf(m2, f.z); m3 = fmaxf(m3, f.w);
    }
    __shared__ float red[32][33];
    __shared__ float bm[32];
    const int ciq = (t & 7) * 4, copy = t >> 3;
    red[ciq + 0][copy] = m0; red[ciq + 1][copy] = m1;
    red[ciq + 2][copy] = m2; red[ciq + 3][copy] = m3;
    __syncthreads();
    if (t < 32) {
        float M = red[t][0];
        for (int c = 1; c < 32; ++c) M = fmaxf(M, red[t][c]);
        bm[t] = M;
    }
    __syncthreads();
    const float M0 = bm[ciq], M1 = bm[ciq + 1], M2 = bm[ciq + 2], M3 = bm[ciq + 3];

    float s0 = 0, s1 = 0, s2 = 0, s3 = 0, T0 = 0, T1 = 0, T2 = 0, T3 = 0;
#pragma unroll 4
    for (int j = 0; j < 32; ++j) {
        float4 f = Bp[t + j * 256];
        float d, e;
        d = f.x - M0; e = __expf(d); s0 += e; T0 += e * d;
        d = f.y - M1; e = __expf(d); s1 += e; T1 += e * d;
        d = f.z - M2; e = __expf(d); s2 += e; T2 += e * d;
        d = f.w - M3; e = __expf(d); s3 += e; T3 += e * d;
    }
    __syncthreads();
    red[ciq + 0][copy] = s0; red[ciq + 1][copy] = s1;
    red[ciq + 2][copy] = s2; red[ciq + 3][copy] = s3;
    __syncthreads();
    if (t < 32) {
        float S = 0;
        for (int c = 0; c < 32; ++c) S += red[t][c];
        ps[bh * 32 + t] = S;
        pm[bh * 32 + t] = bm[t];
    }
    __syncthreads();
    red[ciq + 0][copy] = T0; red[ciq + 1][copy] = T1;
    red[ciq + 2][copy] = T2; red[ciq + 3][copy] = T3;
    __syncthreads();
    if (t < 32) {
        float S = 0;
        for (int c = 0; c < 32; ++c) S += red[t][c];
        pt[bh * 32 + t] = S;
    }
}

// K5: combine 32 h-partials per (b,ci) + entropy scalar.
__global__ __launch_bounds__(256) void k_stats_comb(const float* __restrict__ pm,
                                                    const float* __restrict__ ps,
                                                    const float* __restrict__ pt,
                                                    float* __restrict__ sm,
                                                    float* __restrict__ siz,
                                                    float* __restrict__ d_ent) {
    const int t = threadIdx.x;            // b*32+ci
    const int b = t >> 5;
    float M = -1e30f;
    for (int h = 0; h < 32; ++h) M = fmaxf(M, pm[(b * 32 + h) * 32 + (t & 31)]);
    float Z = 0.0f, T = 0.0f;
    for (int h = 0; h < 32; ++h) {
        const int i = (b * 32 + h) * 32 + (t & 31);
        const float dm = pm[i] - M;
        const float e = __expf(dm);
        Z += ps[i] * e;
        T += e * (pt[i] + ps[i] * dm);
    }
    sm[t] = M;
    siz[t] = 1.0f / Z;
    // ent = (lnZ - T/Z)/ln(32768); eps-in-log shift ~3e-5 << 2e-2 tolerance
    const float ent = (logf(Z) - T / Z) * (1.0f / 10.39720770839918f);
    __shared__ float red[256];
    red[t] = ent;
    __syncthreads();
    for (int s2 = 128; s2 > 0; s2 >>= 1) {
        if (t < s2) red[t] += red[t + s2];
        __syncthreads();
    }
    if (t == 0) *d_ent = red[0] * (1.0f / 256.0f);
}

// ---------------------------------------------------------------------------
// K7: shat [b][h][w][c] -> out [b][c][h][w]  (c already in output order)
__global__ __launch_bounds__(256) void k_out(const float* __restrict__ shat,
                                             float* __restrict__ out) {
    __shared__ float tile[32][129];   // [w][c]
    const int bh = blockIdx.x;
    const int b = bh >> 5, h = bh & 31;
    const int t = threadIdx.x;
    const float4* sp = reinterpret_cast<const float4*>(shat + (size_t)bh * 4096);
#pragma unroll
    for (int j = 0; j < 4; ++j) {
        const int idx = t + j * 256;           // f4 index, 0..1023
        const float4 f = sp[idx];
        const int w = idx >> 5;
        const int c4 = (idx & 31) * 4;
        tile[w][c4 + 0] = f.x; tile[w][c4 + 1] = f.y;
        tile[w][c4 + 2] = f.z; tile[w][c4 + 3] = f.w;
    }
    __syncthreads();
    const int c = t >> 1, half = t & 1;
    float* op = out + (((size_t)b * 128 + c) * 32 + h) * 32 + half * 16;
#pragma unroll
    for (int j = 0; j < 16; ++j) op[j] = tile[half * 16 + j][c];
}

// ---------------------------------------------------------------------------
extern "C" void kernel_launch(void* const* d_in, const int* in_sizes, int n_in,
                              void* d_out, int out_size, void* d_ws, size_t ws_size,
                              hipStream_t stream) {
    const float* in = (const float*)d_in[0];   // (8,32,8,32,32)
    const float* cw = (const float*)d_in[1];   // (128,1,3,3,3)
    const float* cb = (const float*)d_in[2];   // (128,)
    float* out = (float*)d_out;                // 1048576 + 1 floats

    unsigned* xu = (unsigned*)d_ws;            // 16,777,216 u32 = 64 MiB
    float* B    = (float*)(xu + 16777216);     //  8,388,608 f32 = 32 MiB
    float* shat = B + 8388608;                 //  1,048,576 f32 =  4 MiB
    float* pm0  = shat + 1048576;              // [1024*32]
    float* ps0  = pm0 + 32768;
    float* pmF  = ps0 + 32768;                 // [256*32]
    float* psF  = pmF + 8192;
    float* ptF  = psF + 8192;
    float* sm0  = ptF + 8192;                  // [256] each
    float* siz0 = sm0 + 256;
    float* smF  = siz0 + 256;
    float* sizF = smF + 256;

    k_conv1<<<1024, 256, 0, stream>>>(in, cw, cb, xu, B, pm0, ps0);   // conv+B1+stats0p
    k_comb0<<<1, 256, 0, stream>>>(pm0, ps0, sm0, siz0);
    k_iter<0><<<4096, 256, 0, stream>>>(xu, B, sm0, siz0, nullptr);   // -> B2
    k_stats_part<<<256, 256, 0, stream>>>(B, pmF, psF, ptF);
    k_stats_comb<<<1, 256, 0, stream>>>(pmF, psF, ptF, smF, sizF, out + 1048576);
    k_iter<1><<<4096, 256, 0, stream>>>(xu, B, smF, sizF, shat);      // -> S_hat
    k_out<<<256, 256, 0, stream>>>(shat, out);
}

// Round 5
// 124.081 us; speedup vs baseline: 6.1425x; 1.2078x over previous
//
#include <hip/hip_runtime.h>
#include <hip/hip_bf16.h>

#define EPSF 1e-8f

// Workspace:
//   xu   [loc][cp=0..63][ci=0..31]  u32 = (bf16 c=2cp | bf16 c=2cp+1 <<16)   64 MiB
//        loc=(b*32+h)*32+w ; c = cj*4+nj (output channel order)
//   Bpk  [loc][cj=0..31][cip=0..15] u32 = (bf16 B[ci=2cip] | B[2cip+1]<<16)  16 MiB
//   shat [loc][c]  f32 (4 MiB)
//   pm0/ps0 [1024][32] ; pm1/ps1/pt1 [8192][32] ; sm*/siz*/entp [256]
// B in bf16: |B| ~ 1e-6..1e-9, softmax over 32768 -> k uniform to ~1e-6;
// bf16 rounding perturbs k by ~1e-11 relative. Output threshold is 2e-2.

__device__ __forceinline__ float bflo(unsigned u) { return __uint_as_float(u << 16); }
__device__ __forceinline__ float bfhi(unsigned u) { return __uint_as_float(u & 0xffff0000u); }
__device__ __forceinline__ unsigned bfpack2(float a, float b) {
    return (__float_as_uint(a) >> 16) | (__float_as_uint(b) & 0xffff0000u);
}
__device__ __forceinline__ float fastrcp(float x) { return __builtin_amdgcn_rcpf(x); }

// ---------------------------------------------------------------------------
// K1: conv (LDS-staged) + iter0 (uniform k) + B1 (packed bf16) + stats0 partials.
// block 256 = 8 w x 32 ci ; grid 1024 = (b,h,wq). 4 channels/iter -> 4
// independent shfl-reduce chains; launch_bounds(256,4) = VGPR cap 128.
__global__ __launch_bounds__(256, 4) void k_conv1(const float* __restrict__ in,
                                                  const float* __restrict__ cw,
                                                  const float* __restrict__ cb,
                                                  unsigned* __restrict__ xu,
                                                  unsigned* __restrict__ Bpk,
                                                  float* __restrict__ pm0,
                                                  float* __restrict__ ps0) {
    __shared__ float slab[288][17];   // row = ci*9+kd*3+dy ; 16 cols [w0-4,w0+12)
    __shared__ float red[2][8][33];

    const int t = threadIdx.x;
    const int ci = t & 31, lw = t >> 5;
    const int bid = blockIdx.x;
    const int bh = bid >> 2, b = bh >> 5, h = bh & 31;
    const int w0 = (bid & 3) << 3;

    for (int j = t; j < 1152; j += 256) {
        const int r = j >> 2, q = j & 3;
        const int ci2 = r / 9, rem = r - ci2 * 9, kd = rem / 3, dy = rem - kd * 3;
        const int y = h + dy - 1;
        const int x0 = w0 - 4 + q * 4;
        float4 f = {0.f, 0.f, 0.f, 0.f};
        if ((unsigned)y < 32u && (unsigned)x0 < 32u)
            f = *reinterpret_cast<const float4*>(
                in + (((size_t)(b * 32 + ci2) * 8 + kd) * 32 + y) * 32 + x0);
        slab[r][q * 4 + 0] = f.x; slab[r][q * 4 + 1] = f.y;
        slab[r][q * 4 + 2] = f.z; slab[r][q * 4 + 3] = f.w;
    }
    __syncthreads();

    float v[27];
#pragma unroll
    for (int kd = 0; kd < 3; ++kd)
#pragma unroll
        for (int dy = 0; dy < 3; ++dy)
#pragma unroll
            for (int dx = 0; dx < 3; ++dx)
                v[kd * 9 + dy * 3 + dx] = slab[ci * 9 + kd * 3 + dy][lw + 3 + dx];

    const size_t loc = (size_t)bh * 32 + w0 + lw;
    unsigned* xrow = xu + loc * 2048;
    unsigned* Brow = Bpk + loc * 512;
    float Breg[32];

#pragma unroll 2
    for (int cj = 0; cj < 32; ++cj) {
        const float* wp = cw + cj * 108;                 // wave-uniform -> s_load
        float a0 = cb[4 * cj + 0], a1 = cb[4 * cj + 1];
        float a2 = cb[4 * cj + 2], a3 = cb[4 * cj + 3];
#pragma unroll
        for (int k = 0; k < 27; ++k) {
            a0 = fmaf(wp[k], v[k], a0);
            a1 = fmaf(wp[27 + k], v[k], a1);
            a2 = fmaf(wp[54 + k], v[k], a2);
            a3 = fmaf(wp[81 + k], v[k], a3);
        }
        float r0 = a0, r1 = a1, r2 = a2, r3 = a3;        // 4 independent chains
#pragma unroll
        for (int m = 1; m <= 16; m <<= 1) {
            r0 += __shfl_xor(r0, m); r1 += __shfl_xor(r1, m);
            r2 += __shfl_xor(r2, m); r3 += __shfl_xor(r3, m);
        }
        const float S0 = r0 * (1.0f / 32768.0f), S1 = r1 * (1.0f / 32768.0f);
        const float S2 = r2 * (1.0f / 32768.0f), S3 = r3 * (1.0f / 32768.0f);
        const float sh0 = fabsf(S0) * S0 * fastrcp(1.0f + S0 * S0 + EPSF);
        const float sh1 = fabsf(S1) * S1 * fastrcp(1.0f + S1 * S1 + EPSF);
        const float sh2 = fabsf(S2) * S2 * fastrcp(1.0f + S2 * S2 + EPSF);
        const float sh3 = fabsf(S3) * S3 * fastrcp(1.0f + S3 * S3 + EPSF);
        const float bacc = fmaf(sh0, a0, fmaf(sh1, a1, fmaf(sh2, a2, sh3 * a3)));
        Breg[cj] = bacc;
        xrow[(2 * cj) * 32 + ci]     = bfpack2(a0, a1);
        xrow[(2 * cj + 1) * 32 + ci] = bfpack2(a2, a3);
        const float bo = __shfl_xor(bacc, 1);
        if (!(ci & 1)) Brow[cj * 16 + (ci >> 1)] = bfpack2(bacc, bo);
    }

    // stats0 partial: per-(block,ci) max / sum-exp over (8 w, 32 cj)
    float m = Breg[0];
#pragma unroll
    for (int q = 1; q < 32; ++q) m = fmaxf(m, Breg[q]);
    float s = 0.0f;
#pragma unroll
    for (int q = 0; q < 32; ++q) s += __expf(Breg[q] - m);
    red[0][lw][ci] = m; red[1][lw][ci] = s;
    __syncthreads();
    if (lw == 0) {
        float M = red[0][0][ci];
#pragma unroll
        for (int q = 1; q < 8; ++q) M = fmaxf(M, red[0][q][ci]);
        float S = 0.0f;
#pragma unroll
        for (int q = 0; q < 8; ++q) S += red[1][q][ci] * __expf(red[0][q][ci] - M);
        pm0[bid * 32 + ci] = M;
        ps0[bid * 32 + ci] = S;
    }
}

// ---------------------------------------------------------------------------
// Combine NPART partials per (b,ci) -> sm, siz (+ entropy partial if ENT).
template <int NPART, bool ENT>
__global__ __launch_bounds__(256) void k_comb(const float* __restrict__ pm,
                                              const float* __restrict__ ps,
                                              const float* __restrict__ pt,
                                              float* __restrict__ sm,
                                              float* __restrict__ siz,
                                              float* __restrict__ entp) {
    const int b = blockIdx.x, t = threadIdx.x;
    const int ci = t & 31, seg = t >> 5;       // 8 segments
    constexpr int PER = NPART / 8;
    __shared__ float red[3][8][33];

    float M = -1e30f;
    for (int k = 0; k < PER; ++k)
        M = fmaxf(M, pm[((size_t)b * NPART + seg * PER + k) * 32 + ci]);
    red[0][seg][ci] = M;
    __syncthreads();
    float Mg = red[0][0][ci];
#pragma unroll
    for (int q = 1; q < 8; ++q) Mg = fmaxf(Mg, red[0][q][ci]);

    float Z = 0.0f, T = 0.0f;
    for (int k = 0; k < PER; ++k) {
        const size_t i = ((size_t)b * NPART + seg * PER + k) * 32 + ci;
        const float dm = pm[i] - Mg;
        const float e = __expf(dm);
        Z += ps[i] * e;
        if constexpr (ENT) T += (pt[i] + ps[i] * dm) * e;
    }
    red[1][seg][ci] = Z;
    if constexpr (ENT) red[2][seg][ci] = T;
    __syncthreads();
    if (t < 32) {
        float Zt = 0.0f, Tt = 0.0f;
#pragma unroll
        for (int q = 0; q < 8; ++q) {
            Zt += red[1][q][ci];
            if constexpr (ENT) Tt += red[2][q][ci];
        }
        sm[b * 32 + ci] = Mg;
        siz[b * 32 + ci] = 1.0f / Zt;
        if constexpr (ENT)   // ent = (lnZ - T/Z)/ln(32768); eps-in-log ~3e-5
            entp[b * 32 + ci] = (logf(Zt) - Tt / Zt) * (1.0f / 10.39720770839918f);
    }
}

// ---------------------------------------------------------------------------
// Routing iteration. block 256 = 2 loc x (cp=0..63) x 2 ci-halves.
// FINAL=0: B += sum_nj sh*x (packed bf16 r/w) + fused stats partials of B2.
// FINAL=1: write S_hat.
template <int FINAL>
__global__ __launch_bounds__(256, 4) void k_iter(const unsigned* __restrict__ xu,
                                                 unsigned* __restrict__ Bpk,
                                                 const float* __restrict__ sm,
                                                 const float* __restrict__ siz,
                                                 float* __restrict__ shat,
                                                 float* __restrict__ pm,
                                                 float* __restrict__ ps,
                                                 float* __restrict__ pt) {
    __shared__ float s_m[32], s_z[32];
    const int t = threadIdx.x;
    const size_t loc0 = (size_t)blockIdx.x * 2;
    const int b = (int)(loc0 >> 10);
    if (t < 32) { s_m[t] = sm[b * 32 + t]; s_z[t] = siz[b * 32 + t]; }
    __syncthreads();

    const int l = t >> 7, r = t & 127;
    const int cp = r >> 1, half = r & 1, cj = cp >> 1;
    const size_t loc = loc0 + l;

    const uint4* xr = reinterpret_cast<const uint4*>(xu + loc * 2048 + cp * 32 + half * 16);
    const uint4* Br = reinterpret_cast<const uint4*>(Bpk + loc * 512 + cj * 16 + half * 8);

    uint4 xq[4];
#pragma unroll
    for (int j = 0; j < 4; ++j) xq[j] = xr[j];
    const uint4 bq0 = Br[0], bq1 = Br[1];
    const unsigned bu[8] = {bq0.x, bq0.y, bq0.z, bq0.w, bq1.x, bq1.y, bq1.z, bq1.w};
    float bv[16];
#pragma unroll
    for (int e = 0; e < 8; ++e) { bv[2 * e] = bflo(bu[e]); bv[2 * e + 1] = bfhi(bu[e]); }

    float kk[16];
#pragma unroll
    for (int q = 0; q < 16; ++q)
        kk[q] = __expf(bv[q] - s_m[half * 16 + q]) * s_z[half * 16 + q];

    float S0 = 0.0f, S1 = 0.0f;
#pragma unroll
    for (int j = 0; j < 4; ++j) {
        const unsigned xw[4] = {xq[j].x, xq[j].y, xq[j].z, xq[j].w};
#pragma unroll
        for (int q = 0; q < 4; ++q) {
            S0 = fmaf(kk[j * 4 + q], bflo(xw[q]), S0);
            S1 = fmaf(kk[j * 4 + q], bfhi(xw[q]), S1);
        }
    }
    S0 += __shfl_xor(S0, 1);                 // combine ci halves
    S1 += __shfl_xor(S1, 1);
    const float sh0 = fabsf(S0) * S0 * fastrcp(1.0f + S0 * S0 + EPSF);
    const float sh1 = fabsf(S1) * S1 * fastrcp(1.0f + S1 * S1 + EPSF);

    if constexpr (FINAL) {
        if (half == 0)
            reinterpret_cast<float2*>(shat)[loc * 64 + cp] = make_float2(sh0, sh1);
    } else {
        __shared__ __align__(16) float Bl[2][32][36];
        float d[16];
#pragma unroll
        for (int j = 0; j < 4; ++j) {
            const unsigned xw[4] = {xq[j].x, xq[j].y, xq[j].z, xq[j].w};
#pragma unroll
            for (int q = 0; q < 4; ++q)
                d[j * 4 + q] = fmaf(sh0, bflo(xw[q]), sh1 * bfhi(xw[q]));
        }
#pragma unroll
        for (int q = 0; q < 16; ++q) d[q] += __shfl_xor(d[q], 2);   // sum over njh
        if (!(r & 2)) {                     // owner: one thread per (loc,cj,half)
            float o[16];
#pragma unroll
            for (int q = 0; q < 16; ++q) o[q] = bv[q] + d[q];
            unsigned pk[8];
#pragma unroll
            for (int e = 0; e < 8; ++e) pk[e] = bfpack2(o[2 * e], o[2 * e + 1]);
            uint4* Bw = reinterpret_cast<uint4*>(Bpk + loc * 512 + cj * 16 + half * 8);
            Bw[0] = make_uint4(pk[0], pk[1], pk[2], pk[3]);
            Bw[1] = make_uint4(pk[4], pk[5], pk[6], pk[7]);
            float4* dst = reinterpret_cast<float4*>(&Bl[l][cj][half * 16]);
            dst[0] = make_float4(o[0], o[1], o[2], o[3]);
            dst[1] = make_float4(o[4], o[5], o[6], o[7]);
            dst[2] = make_float4(o[8], o[9], o[10], o[11]);
            dst[3] = make_float4(o[12], o[13], o[14], o[15]);
        }
        __syncthreads();
        // fused stats partials of B2: per (loc,ci) over 32 cj, quad-split
        const int l2 = t >> 7, ci = (t >> 2) & 31, qq = t & 3;
        float B8[8];
#pragma unroll
        for (int i = 0; i < 8; ++i) B8[i] = Bl[l2][qq * 8 + i][ci];
        float m = B8[0];
#pragma unroll
        for (int i = 1; i < 8; ++i) m = fmaxf(m, B8[i]);
        m = fmaxf(m, __shfl_xor(m, 1));
        m = fmaxf(m, __shfl_xor(m, 2));
        float s = 0.0f, T = 0.0f;
#pragma unroll
        for (int i = 0; i < 8; ++i) {
            const float dd = B8[i] - m;
            const float e = __expf(dd);
            s += e; T += e * dd;
        }
        s += __shfl_xor(s, 1); s += __shfl_xor(s, 2);
        T += __shfl_xor(T, 1); T += __shfl_xor(T, 2);
        if (qq == 0) {
            const size_t row = (size_t)blockIdx.x * 2 + l2;
            pm[row * 32 + ci] = m;
            ps[row * 32 + ci] = s;
            pt[row * 32 + ci] = T;
        }
    }
}

// ---------------------------------------------------------------------------
// K6: shat [b][h][w][c] -> out [b][c][h][w] ; block 0 also finalizes entropy.
__global__ __launch_bounds__(256) void k_out(const float* __restrict__ shat,
                                             const float* __restrict__ entp,
                                             float* __restrict__ out) {
    __shared__ float tile[32][129];   // [w][c]
    const int bh = blockIdx.x;
    const int b = bh >> 5, h = bh & 31;
    const int t = threadIdx.x;
    const float4* sp = reinterpret_cast<const float4*>(shat + (size_t)bh * 4096);
#pragma unroll
    for (int j = 0; j < 4; ++j) {
        const int idx = t + j * 256;
        const float4 f = sp[idx];
        const int w = idx >> 5;
        const int c4 = (idx & 31) * 4;
        tile[w][c4 + 0] = f.x; tile[w][c4 + 1] = f.y;
        tile[w][c4 + 2] = f.z; tile[w][c4 + 3] = f.w;
    }
    __syncthreads();
    const int c = t >> 1, half = t & 1;
    float* op = out + (((size_t)b * 128 + c) * 32 + h) * 32 + half * 16;
#pragma unroll
    for (int j = 0; j < 16; ++j) op[j] = tile[half * 16 + j][c];

    if (bh == 0) {
        __shared__ float er[256];
        er[t] = entp[t];
        __syncthreads();
        for (int s2 = 128; s2 > 0; s2 >>= 1) {
            if (t < s2) er[t] += er[t + s2];
            __syncthreads();
        }
        if (t == 0) out[1048576] = er[0] * (1.0f / 256.0f);
    }
}

// ---------------------------------------------------------------------------
extern "C" void kernel_launch(void* const* d_in, const int* in_sizes, int n_in,
                              void* d_out, int out_size, void* d_ws, size_t ws_size,
                              hipStream_t stream) {
    const float* in = (const float*)d_in[0];   // (8,32,8,32,32)
    const float* cw = (const float*)d_in[1];   // (128,1,3,3,3)
    const float* cb = (const float*)d_in[2];   // (128,)
    float* out = (float*)d_out;                // 1048576 + 1 floats

    unsigned* xu  = (unsigned*)d_ws;           // 16,777,216 u32 = 64 MiB
    unsigned* Bpk = xu + 16777216;             //  4,194,304 u32 = 16 MiB
    float* shat = (float*)(Bpk + 4194304);     //  1,048,576 f32 =  4 MiB
    float* pm0  = shat + 1048576;              // [1024*32]
    float* ps0  = pm0 + 32768;
    float* pm1  = ps0 + 32768;                 // [8192*32]
    float* ps1  = pm1 + 262144;
    float* pt1  = ps1 + 262144;
    float* sm0  = pt1 + 262144;                // [256] each
    float* siz0 = sm0 + 256;
    float* sm1  = siz0 + 256;
    float* siz1 = sm1 + 256;
    float* entp = siz1 + 256;

    k_conv1<<<1024, 256, 0, stream>>>(in, cw, cb, xu, Bpk, pm0, ps0);
    k_comb<128, false><<<8, 256, 0, stream>>>(pm0, ps0, nullptr, sm0, siz0, nullptr);
    k_iter<0><<<4096, 256, 0, stream>>>(xu, Bpk, sm0, siz0, nullptr, pm1, ps1, pt1);
    k_comb<1024, true><<<8, 256, 0, stream>>>(pm1, ps1, pt1, sm1, siz1, entp);
    k_iter<1><<<4096, 256, 0, stream>>>(xu, Bpk, sm1, siz1, shat, nullptr, nullptr, nullptr);
    k_out<<<256, 256, 0, stream>>>(shat, entp, out);
}

// Round 6
// 123.638 us; speedup vs baseline: 6.1645x; 1.0036x over previous
//
#include <hip/hip_runtime.h>
#include <hip/hip_bf16.h>

#define EPSF 1e-8f

// Workspace:
//   xu   [loc][cp=0..63][ci=0..31]  u32 = (bf16 c=2cp | bf16 c=2cp+1 <<16)   64 MiB
//        loc=(b*32+h)*32+w ; c = cj*4+nj (output channel order)
//   Bpk  [loc][cj=0..31][cip=0..15] u32 = (bf16 B[ci=2cip] | B[2cip+1]<<16)  16 MiB
//   shat [loc][c]  f32 (4 MiB)
//   pm0/ps0 [1024][32] ; pm1/ps1/pt1 [8192][32] ; sm*/siz*/entp [256]

__device__ __forceinline__ float bflo(unsigned u) { return __uint_as_float(u << 16); }
__device__ __forceinline__ float bfhi(unsigned u) { return __uint_as_float(u & 0xffff0000u); }
__device__ __forceinline__ unsigned bfpack2(float a, float b) {
    return (__float_as_uint(a) >> 16) | (__float_as_uint(b) & 0xffff0000u);
}
__device__ __forceinline__ float fastrcp(float x) { return __builtin_amdgcn_rcpf(x); }

// ---------------------------------------------------------------------------
// K1: conv + iter0 + B1 + stats0 partials.
// Key identity: iter0's S(loc,c) = (sum_k w[c,k]*vsum[k] + 32*cb[c])/32768
// where vsum = ci-summed taps -> squash table shl[lw][c] computed ONCE in the
// prologue; the 32-iteration channel loop has no shuffles / no rcp.
__global__ __launch_bounds__(256, 4) void k_conv1(const float* __restrict__ in,
                                                  const float* __restrict__ cw,
                                                  const float* __restrict__ cb,
                                                  unsigned* __restrict__ xu,
                                                  unsigned* __restrict__ Bpk,
                                                  float* __restrict__ pm0,
                                                  float* __restrict__ ps0) {
    __shared__ float slab[288][17];   // row = ci*9+kd*3+dy ; 16 cols [w0-4,w0+12)
    __shared__ float wT[27][129];     // transposed weights; 129: stride%32==1
    __shared__ float shl[8][128];     // squash values per (lw, c)
    __shared__ float red[2][8][33];

    const int t = threadIdx.x;
    const int ci = t & 31, lw = t >> 5;
    const int bid = blockIdx.x;
    const int bh = bid >> 2, b = bh >> 5, h = bh & 31;
    const int w0 = (bid & 3) << 3;

    // coalesced slab staging (zero-padded OOB)
    for (int j = t; j < 1152; j += 256) {
        const int r = j >> 2, q = j & 3;
        const int ci2 = r / 9, rem = r - ci2 * 9, kd = rem / 3, dy = rem - kd * 3;
        const int y = h + dy - 1;
        const int x0 = w0 - 4 + q * 4;
        float4 f = {0.f, 0.f, 0.f, 0.f};
        if ((unsigned)y < 32u && (unsigned)x0 < 32u)
            f = *reinterpret_cast<const float4*>(
                in + (((size_t)(b * 32 + ci2) * 8 + kd) * 32 + y) * 32 + x0);
        slab[r][q * 4 + 0] = f.x; slab[r][q * 4 + 1] = f.y;
        slab[r][q * 4 + 2] = f.z; slab[r][q * 4 + 3] = f.w;
    }
    // weight transpose -> LDS (coalesced reads; writes stride 129 -> no conflict)
    for (int j = t; j < 3456; j += 256) {
        const int c = j / 27, k = j - c * 27;
        wT[k][c] = cw[j];
    }
    __syncthreads();

    float v[27];
#pragma unroll
    for (int kd = 0; kd < 3; ++kd)
#pragma unroll
        for (int dy = 0; dy < 3; ++dy)
#pragma unroll
            for (int dx = 0; dx < 3; ++dx)
                v[kd * 9 + dy * 3 + dx] = slab[ci * 9 + kd * 3 + dy][lw + 3 + dx];

    // one-time tap sum across the 32 ci lanes (xor masks stay in half-wave)
    float vs[27];
#pragma unroll
    for (int k = 0; k < 27; ++k) {
        float r = v[k];
        r += __shfl_xor(r, 1); r += __shfl_xor(r, 2); r += __shfl_xor(r, 4);
        r += __shfl_xor(r, 8); r += __shfl_xor(r, 16);
        vs[k] = r;
    }
    // squash table: thread (lw,ci) computes channels c = ci+32q
#pragma unroll
    for (int q = 0; q < 4; ++q) {
        const int c = ci + 32 * q;
        float acc = 32.0f * cb[c];
#pragma unroll
        for (int k = 0; k < 27; ++k) acc = fmaf(wT[k][c], vs[k], acc);
        const float S = acc * (1.0f / 32768.0f);
        shl[lw][c] = fabsf(S) * S * fastrcp(1.0f + S * S + EPSF);
    }
    __syncthreads();

    const size_t loc = (size_t)bh * 32 + w0 + lw;
    unsigned* xrow = xu + loc * 2048;
    unsigned* Brow = Bpk + loc * 512;
    float Breg[32];

#pragma unroll 2
    for (int cj = 0; cj < 32; ++cj) {
        const float* wp = cw + cj * 108;                 // wave-uniform -> s_load
        float a0 = cb[4 * cj + 0], a1 = cb[4 * cj + 1];
        float a2 = cb[4 * cj + 2], a3 = cb[4 * cj + 3];
#pragma unroll
        for (int k = 0; k < 27; ++k) {
            a0 = fmaf(wp[k], v[k], a0);
            a1 = fmaf(wp[27 + k], v[k], a1);
            a2 = fmaf(wp[54 + k], v[k], a2);
            a3 = fmaf(wp[81 + k], v[k], a3);
        }
        const float4 sh4 = *reinterpret_cast<const float4*>(&shl[lw][4 * cj]);
        const float bacc = fmaf(sh4.x, a0, fmaf(sh4.y, a1,
                           fmaf(sh4.z, a2, sh4.w * a3)));
        Breg[cj] = bacc;
        xrow[(2 * cj) * 32 + ci]     = bfpack2(a0, a1);
        xrow[(2 * cj + 1) * 32 + ci] = bfpack2(a2, a3);
        const float bo = __shfl_xor(bacc, 1);
        if (!(ci & 1)) Brow[cj * 16 + (ci >> 1)] = bfpack2(bacc, bo);
    }

    // stats0 partial: per-(block,ci) max / sum-exp over (8 w, 32 cj)
    float m = Breg[0];
#pragma unroll
    for (int q = 1; q < 32; ++q) m = fmaxf(m, Breg[q]);
    float s = 0.0f;
#pragma unroll
    for (int q = 0; q < 32; ++q) s += __expf(Breg[q] - m);
    red[0][lw][ci] = m; red[1][lw][ci] = s;
    __syncthreads();
    if (lw == 0) {
        float M = red[0][0][ci];
#pragma unroll
        for (int q = 1; q < 8; ++q) M = fmaxf(M, red[0][q][ci]);
        float S = 0.0f;
#pragma unroll
        for (int q = 0; q < 8; ++q) S += red[1][q][ci] * __expf(red[0][q][ci] - M);
        pm0[bid * 32 + ci] = M;
        ps0[bid * 32 + ci] = S;
    }
}

// ---------------------------------------------------------------------------
// Combine NPART partials per (b,ci) -> sm, siz (+ entropy partial if ENT).
template <int NPART, bool ENT>
__global__ __launch_bounds__(256) void k_comb(const float* __restrict__ pm,
                                              const float* __restrict__ ps,
                                              const float* __restrict__ pt,
                                              float* __restrict__ sm,
                                              float* __restrict__ siz,
                                              float* __restrict__ entp) {
    const int b = blockIdx.x, t = threadIdx.x;
    const int ci = t & 31, seg = t >> 5;       // 8 segments
    constexpr int PER = NPART / 8;
    __shared__ float red[3][8][33];

    float M = -1e30f;
    for (int k = 0; k < PER; ++k)
        M = fmaxf(M, pm[((size_t)b * NPART + seg * PER + k) * 32 + ci]);
    red[0][seg][ci] = M;
    __syncthreads();
    float Mg = red[0][0][ci];
#pragma unroll
    for (int q = 1; q < 8; ++q) Mg = fmaxf(Mg, red[0][q][ci]);

    float Z = 0.0f, T = 0.0f;
    for (int k = 0; k < PER; ++k) {
        const size_t i = ((size_t)b * NPART + seg * PER + k) * 32 + ci;
        const float dm = pm[i] - Mg;
        const float e = __expf(dm);
        Z += ps[i] * e;
        if constexpr (ENT) T += (pt[i] + ps[i] * dm) * e;
    }
    red[1][seg][ci] = Z;
    if constexpr (ENT) red[2][seg][ci] = T;
    __syncthreads();
    if (t < 32) {
        float Zt = 0.0f, Tt = 0.0f;
#pragma unroll
        for (int q = 0; q < 8; ++q) {
            Zt += red[1][q][ci];
            if constexpr (ENT) Tt += red[2][q][ci];
        }
        sm[b * 32 + ci] = Mg;
        siz[b * 32 + ci] = 1.0f / Zt;
        if constexpr (ENT)   // ent = (lnZ - T/Z)/ln(32768); eps-in-log ~3e-5
            entp[b * 32 + ci] = (logf(Zt) - Tt / Zt) * (1.0f / 10.39720770839918f);
    }
}

// ---------------------------------------------------------------------------
// Routing iteration. block 256 = 2 loc x (cp=0..63) x 2 ci-halves.
// FINAL=0: B += sum_nj sh*x (packed bf16 r/w) + fused stats partials of B2.
// FINAL=1: write S_hat.
template <int FINAL>
__global__ __launch_bounds__(256, 4) void k_iter(const unsigned* __restrict__ xu,
                                                 unsigned* __restrict__ Bpk,
                                                 const float* __restrict__ sm,
                                                 const float* __restrict__ siz,
                                                 float* __restrict__ shat,
                                                 float* __restrict__ pm,
                                                 float* __restrict__ ps,
                                                 float* __restrict__ pt) {
    __shared__ float s_m[32], s_z[32];
    const int t = threadIdx.x;
    const size_t loc0 = (size_t)blockIdx.x * 2;
    const int b = (int)(loc0 >> 10);
    if (t < 32) { s_m[t] = sm[b * 32 + t]; s_z[t] = siz[b * 32 + t]; }
    __syncthreads();

    const int l = t >> 7, r = t & 127;
    const int cp = r >> 1, half = r & 1, cj = cp >> 1;
    const size_t loc = loc0 + l;

    const uint4* xr = reinterpret_cast<const uint4*>(xu + loc * 2048 + cp * 32 + half * 16);
    const uint4* Br = reinterpret_cast<const uint4*>(Bpk + loc * 512 + cj * 16 + half * 8);

    uint4 xq[4];
#pragma unroll
    for (int j = 0; j < 4; ++j) xq[j] = xr[j];
    const uint4 bq0 = Br[0], bq1 = Br[1];
    const unsigned bu[8] = {bq0.x, bq0.y, bq0.z, bq0.w, bq1.x, bq1.y, bq1.z, bq1.w};
    float bv[16];
#pragma unroll
    for (int e = 0; e < 8; ++e) { bv[2 * e] = bflo(bu[e]); bv[2 * e + 1] = bfhi(bu[e]); }

    float kk[16];
#pragma unroll
    for (int q = 0; q < 16; ++q)
        kk[q] = __expf(bv[q] - s_m[half * 16 + q]) * s_z[half * 16 + q];

    float S0 = 0.0f, S1 = 0.0f;
#pragma unroll
    for (int j = 0; j < 4; ++j) {
        const unsigned xw[4] = {xq[j].x, xq[j].y, xq[j].z, xq[j].w};
#pragma unroll
        for (int q = 0; q < 4; ++q) {
            S0 = fmaf(kk[j * 4 + q], bflo(xw[q]), S0);
            S1 = fmaf(kk[j * 4 + q], bfhi(xw[q]), S1);
        }
    }
    S0 += __shfl_xor(S0, 1);                 // combine ci halves
    S1 += __shfl_xor(S1, 1);
    const float sh0 = fabsf(S0) * S0 * fastrcp(1.0f + S0 * S0 + EPSF);
    const float sh1 = fabsf(S1) * S1 * fastrcp(1.0f + S1 * S1 + EPSF);

    if constexpr (FINAL) {
        if (half == 0)
            reinterpret_cast<float2*>(shat)[loc * 64 + cp] = make_float2(sh0, sh1);
    } else {
        __shared__ __align__(16) float Bl[2][32][36];
        float d[16];
#pragma unroll
        for (int j = 0; j < 4; ++j) {
            const unsigned xw[4] = {xq[j].x, xq[j].y, xq[j].z, xq[j].w};
#pragma unroll
            for (int q = 0; q < 4; ++q)
                d[j * 4 + q] = fmaf(sh0, bflo(xw[q]), sh1 * bfhi(xw[q]));
        }
#pragma unroll
        for (int q = 0; q < 16; ++q) d[q] += __shfl_xor(d[q], 2);   // sum over njh
        if (!(r & 2)) {                     // owner: one thread per (loc,cj,half)
            float o[16];
#pragma unroll
            for (int q = 0; q < 16; ++q) o[q] = bv[q] + d[q];
            unsigned pk[8];
#pragma unroll
            for (int e = 0; e < 8; ++e) pk[e] = bfpack2(o[2 * e], o[2 * e + 1]);
            uint4* Bw = reinterpret_cast<uint4*>(Bpk + loc * 512 + cj * 16 + half * 8);
            Bw[0] = make_uint4(pk[0], pk[1], pk[2], pk[3]);
            Bw[1] = make_uint4(pk[4], pk[5], pk[6], pk[7]);
            float4* dst = reinterpret_cast<float4*>(&Bl[l][cj][half * 16]);
            dst[0] = make_float4(o[0], o[1], o[2], o[3]);
            dst[1] = make_float4(o[4], o[5], o[6], o[7]);
            dst[2] = make_float4(o[8], o[9], o[10], o[11]);
            dst[3] = make_float4(o[12], o[13], o[14], o[15]);
        }
        __syncthreads();
        // fused stats partials of B2: per (loc,ci) over 32 cj, quad-split
        const int l2 = t >> 7, ci = (t >> 2) & 31, qq = t & 3;
        float B8[8];
#pragma unroll
        for (int i = 0; i < 8; ++i) B8[i] = Bl[l2][qq * 8 + i][ci];
        float m = B8[0];
#pragma unroll
        for (int i = 1; i < 8; ++i) m = fmaxf(m, B8[i]);
        m = fmaxf(m, __shfl_xor(m, 1));
        m = fmaxf(m, __shfl_xor(m, 2));
        float s = 0.0f, T = 0.0f;
#pragma unroll
        for (int i = 0; i < 8; ++i) {
            const float dd = B8[i] - m;
            const float e = __expf(dd);
            s += e; T += e * dd;
        }
        s += __shfl_xor(s, 1); s += __shfl_xor(s, 2);
        T += __shfl_xor(T, 1); T += __shfl_xor(T, 2);
        if (qq == 0) {
            const size_t row = (size_t)blockIdx.x * 2 + l2;
            pm[row * 32 + ci] = m;
            ps[row * 32 + ci] = s;
            pt[row * 32 + ci] = T;
        }
    }
}

// ---------------------------------------------------------------------------
// K6: shat [b][h][w][c] -> out [b][c][h][w] ; block 0 also finalizes entropy.
__global__ __launch_bounds__(256) void k_out(const float* __restrict__ shat,
                                             const float* __restrict__ entp,
                                             float* __restrict__ out) {
    __shared__ float tile[32][129];   // [w][c]
    const int bh = blockIdx.x;
    const int b = bh >> 5, h = bh & 31;
    const int t = threadIdx.x;
    const float4* sp = reinterpret_cast<const float4*>(shat + (size_t)bh * 4096);
#pragma unroll
    for (int j = 0; j < 4; ++j) {
        const int idx = t + j * 256;
        const float4 f = sp[idx];
        const int w = idx >> 5;
        const int c4 = (idx & 31) * 4;
        tile[w][c4 + 0] = f.x; tile[w][c4 + 1] = f.y;
        tile[w][c4 + 2] = f.z; tile[w][c4 + 3] = f.w;
    }
    __syncthreads();
    const int c = t >> 1, half = t & 1;
    float* op = out + (((size_t)b * 128 + c) * 32 + h) * 32 + half * 16;
#pragma unroll
    for (int j = 0; j < 16; ++j) op[j] = tile[half * 16 + j][c];

    if (bh == 0) {
        __shared__ float er[256];
        er[t] = entp[t];
        __syncthreads();
        for (int s2 = 128; s2 > 0; s2 >>= 1) {
            if (t < s2) er[t] += er[t + s2];
            __syncthreads();
        }
        if (t == 0) out[1048576] = er[0] * (1.0f / 256.0f);
    }
}

// ---------------------------------------------------------------------------
extern "C" void kernel_launch(void* const* d_in, const int* in_sizes, int n_in,
                              void* d_out, int out_size, void* d_ws, size_t ws_size,
                              hipStream_t stream) {
    const float* in = (const float*)d_in[0];   // (8,32,8,32,32)
    const float* cw = (const float*)d_in[1];   // (128,1,3,3,3)
    const float* cb = (const float*)d_in[2];   // (128,)
    float* out = (float*)d_out;                // 1048576 + 1 floats

    unsigned* xu  = (unsigned*)d_ws;           // 16,777,216 u32 = 64 MiB
    unsigned* Bpk = xu + 16777216;             //  4,194,304 u32 = 16 MiB
    float* shat = (float*)(Bpk + 4194304);     //  1,048,576 f32 =  4 MiB
    float* pm0  = shat + 1048576;              // [1024*32]
    float* ps0  = pm0 + 32768;
    float* pm1  = ps0 + 32768;                 // [8192*32]
    float* ps1  = pm1 + 262144;
    float* pt1  = ps1 + 262144;
    float* sm0  = pt1 + 262144;                // [256] each
    float* siz0 = sm0 + 256;
    float* sm1  = siz0 + 256;
    float* siz1 = sm1 + 256;
    float* entp = siz1 + 256;

    k_conv1<<<1024, 256, 0, stream>>>(in, cw, cb, xu, Bpk, pm0, ps0);
    k_comb<128, false><<<8, 256, 0, stream>>>(pm0, ps0, nullptr, sm0, siz0, nullptr);
    k_iter<0><<<4096, 256, 0, stream>>>(xu, Bpk, sm0, siz0, nullptr, pm1, ps1, pt1);
    k_comb<1024, true><<<8, 256, 0, stream>>>(pm1, ps1, pt1, sm1, siz1, entp);
    k_iter<1><<<4096, 256, 0, stream>>>(xu, Bpk, sm1, siz1, shat, nullptr, nullptr, nullptr);
    k_out<<<256, 256, 0, stream>>>(shat, entp, out);
}